// Round 19
// baseline (167.159 us; speedup 1.0000x reference)
//
#include <hip/hip_runtime.h>

#define D 128
#define BSZ 64             // dst nodes per bucket
#define CHUNK 8192         // edges per scatter block
#define CAPG 1536          // staging slots per bucket (mean ~767, sigma ~28)
#define SPILL_MAX 65536

typedef __attribute__((ext_vector_type(8))) short short8;
typedef __attribute__((ext_vector_type(4))) float f32x4;
typedef __attribute__((ext_vector_type(2))) float f32x2;

__device__ inline unsigned short f2b(float f) {
    union { float f; unsigned int u; } x; x.f = f;
    unsigned int r = x.u + 0x7FFFu + ((x.u >> 16) & 1u);
    return (unsigned short)(r >> 16);
}

// ---------------------------------------------------------------------------
// prep_scatter (fused, 1024-thread blocks, cursors pre-zeroed by memset):
//   [0, nblkS)            bucket scatter, register-staged edges, 16 waves/blk
//   [nblkS, +nConvH)      h fp32 -> bf16 (GEMM) AND fp8-e4m3 (gather)
//   [.., +10)             W fragment packing
//   [last]                bias sum
// ---------------------------------------------------------------------------
__global__ __launch_bounds__(1024) void prep_scatter(
    const int* __restrict__ s_uu, const int* __restrict__ d_uu, int E_uu,
    const int* __restrict__ s_iu, const int* __restrict__ d_iu, int E_iu,
    const int* __restrict__ s_ui, const int* __restrict__ d_ui, int E_ui,
    int NB0, int NB1,
    int* __restrict__ cursors, int* __restrict__ stg,
    int2* __restrict__ spill, int* __restrict__ spillCnt,
    int nblk0, int nblk1, int nblkS,
    const float* __restrict__ hU, const float* __restrict__ hI,
    int nU8, int nI8,
    unsigned short* __restrict__ hbU, unsigned short* __restrict__ hbI,
    unsigned char* __restrict__ h8U, unsigned char* __restrict__ h8I,
    const float* __restrict__ Wself_uu, const float* __restrict__ Wself_iu,
    const float* __restrict__ Wneigh_uu, const float* __restrict__ Wneigh_iu,
    const float* __restrict__ Wself_ui, const float* __restrict__ Wneigh_ui,
    short8* __restrict__ WfU0, short8* __restrict__ WfU1, short8* __restrict__ WfU2,
    short8* __restrict__ WfI0, short8* __restrict__ WfI1,
    const float* __restrict__ b_uu, const float* __restrict__ b_iu,
    float* __restrict__ bsum, int nConvH)
{
    __shared__ int hist[1024];
    __shared__ int bbase[1024];
    const int t = threadIdx.x;

    if (blockIdx.x >= nblkS) {
        const int cb = blockIdx.x - nblkS;
        if (cb < nConvH) {
            // ---- h conversion: 8 floats per thread ----
            int g = cb * 1024 + t;
            const float* src; unsigned short* dst; unsigned char* dst8;
            if (g < nU8) {
                src = hU + (size_t)g * 8; dst = hbU + (size_t)g * 8;
                dst8 = h8U + (size_t)g * 8;
            } else {
                g -= nU8;
                if (g >= nI8) return;
                src = hI + (size_t)g * 8; dst = hbI + (size_t)g * 8;
                dst8 = h8I + (size_t)g * 8;
            }
            const float4 a = *reinterpret_cast<const float4*>(src);
            const float4 c = *reinterpret_cast<const float4*>(src + 4);
            short8 o;
            o[0] = (short)f2b(a.x); o[1] = (short)f2b(a.y);
            o[2] = (short)f2b(a.z); o[3] = (short)f2b(a.w);
            o[4] = (short)f2b(c.x); o[5] = (short)f2b(c.y);
            o[6] = (short)f2b(c.z); o[7] = (short)f2b(c.w);
            *reinterpret_cast<short8*>(dst) = o;
            unsigned int p0 = __builtin_amdgcn_cvt_pk_fp8_f32(a.x, a.y, 0, false);
            p0 = __builtin_amdgcn_cvt_pk_fp8_f32(a.z, a.w, p0, true);
            unsigned int p1 = __builtin_amdgcn_cvt_pk_fp8_f32(c.x, c.y, 0, false);
            p1 = __builtin_amdgcn_cvt_pk_fp8_f32(c.z, c.w, p1, true);
            *reinterpret_cast<uint2*>(dst8) = make_uint2(p0, p1);
            return;
        }
        const int wb = cb - nConvH;
        if (wb < 10) {
            // ---- W fragment packing: weight wb>>1, half wb&1 ----
            const float* Wa; const float* Wb = nullptr; short8* Wf;
            switch (wb >> 1) {
                case 0: Wa = Wself_uu; Wb = Wself_iu; Wf = WfU0; break;
                case 1: Wa = Wneigh_uu; Wf = WfU1; break;
                case 2: Wa = Wneigh_iu; Wf = WfU2; break;
                case 3: Wa = Wself_ui;  Wf = WfI0; break;
                default: Wa = Wneigh_ui; Wf = WfI1; break;
            }
            int t2 = (wb & 1) * 1024 + t;           // 0..2047
            int c  = t2 >> 8;
            int kc = (t2 >> 6) & 3;
            int l  = t2 & 63;
            int n  = c * 16 + (l & 15);
            int k0 = kc * 32 + ((l >> 4) << 3);
            short8 o;
#pragma unroll
            for (int j = 0; j < 8; ++j) {
                float v = Wa[(k0 + j) * D + n];
                if (Wb) v += Wb[(k0 + j) * D + n];
                o[j] = (short)f2b(v);
            }
            Wf[t2] = o;
            return;
        }
        if (t < D) bsum[t] = b_uu[t] + b_iu[t];
        return;
    }

    // ---------------- scatter: register-staged, 2 LDS passes ----------------
    const int* src; const int* dst; int E; int relBase; int b0;
    if (blockIdx.x < nblk0) {
        b0 = blockIdx.x; src = s_uu; dst = d_uu; E = E_uu; relBase = 0;
    } else if (blockIdx.x < nblk0 + nblk1) {
        b0 = blockIdx.x - nblk0; src = s_iu; dst = d_iu; E = E_iu; relBase = NB0;
    } else {
        b0 = blockIdx.x - nblk0 - nblk1; src = s_ui; dst = d_ui; E = E_ui;
        relBase = NB0 + NB1;
    }
    const int mye = b0 * CHUNK + t * 8;      // this thread's 8 edges
    const int nv  = min(8, max(0, E - mye)); // valid count

    int ed[8], es[8];
    if (nv == 8) {
        *reinterpret_cast<int4*>(&ed[0]) = *reinterpret_cast<const int4*>(dst + mye);
        *reinterpret_cast<int4*>(&ed[4]) = *reinterpret_cast<const int4*>(dst + mye + 4);
        *reinterpret_cast<int4*>(&es[0]) = *reinterpret_cast<const int4*>(src + mye);
        *reinterpret_cast<int4*>(&es[4]) = *reinterpret_cast<const int4*>(src + mye + 4);
    } else {
        for (int j = 0; j < 8; ++j) {
            ed[j] = (j < nv) ? dst[mye + j] : 0;
            es[j] = (j < nv) ? src[mye + j] : 0;
        }
    }

    hist[t] = 0;
    __syncthreads();

#pragma unroll
    for (int j = 0; j < 8; ++j)
        if (j < nv) atomicAdd(&hist[ed[j] >> 6], 1);
    __syncthreads();

    {
        int c = hist[t];
        bbase[t] = c ? ((relBase + t) * CAPG + atomicAdd(&cursors[relBase + t], c)) : 0;
        hist[t] = 0;    // reuse as rank counter
    }
    __syncthreads();

#pragma unroll
    for (int j = 0; j < 8; ++j) {
        if (j < nv) {
            int dv = ed[j];
            int bkt = dv >> 6;
            int g = relBase + bkt;
            int r = atomicAdd(&hist[bkt], 1);
            int pos = bbase[bkt] + r;
            int packed = (es[j] & 0x1FFFF) | ((dv & 63) << 17);
            if (pos < (g + 1) * CAPG) {
                stg[pos] = packed;
            } else {
                int si = atomicAdd(spillCnt, 1);
                if (si < SPILL_MAX) spill[si] = make_int2(g, packed);
            }
        }
    }
}

// ---------------------------------------------------------------------------
// gather_bucket: one block per 64-node bucket. Counting-sort the ~767-edge
// window into 6KB LDS, then R17's pipelined per-node gather with WIDER
// loads: uint4 per lane, 8 lanes per 128B row, 8 rows in flight per load.
// fp8 rows (HW cvt), bf16 means. 4 waves x 16 nodes.
// ---------------------------------------------------------------------------
__global__ __launch_bounds__(256) void gather_bucket(
    const unsigned char* __restrict__ h8U, const unsigned char* __restrict__ h8I,
    const int* __restrict__ stg, const int* __restrict__ cursors,
    const int2* __restrict__ spill, const int* __restrict__ spillCnt,
    unsigned short* __restrict__ accUU, unsigned short* __restrict__ accIU,
    unsigned short* __restrict__ accUI,
    int NB0, int NB1, int NU, int NI)
{
    __shared__ int sidx[CAPG];      // 6 KB sorted edge sources
    __shared__ int cnt[BSZ];
    __shared__ int st2[BSZ];
    __shared__ int rank[BSZ];
    __shared__ int sc[BSZ];
    __shared__ int spillN_s;

    const int b = blockIdx.x;
    const unsigned char* h8; unsigned short* acc; int N; int lb;
    if (b < NB0)            { lb = b;             h8 = h8U; acc = accUU; N = NU; }
    else if (b < NB0 + NB1) { lb = b - NB0;       h8 = h8I; acc = accIU; N = NU; }
    else                    { lb = b - NB0 - NB1; h8 = h8U; acc = accUI; N = NI; }

    const int t = threadIdx.x;
    const int node0 = lb * BSZ;
    const int base  = b * CAPG;
    const int end   = base + min(cursors[b], CAPG);

    if (t < BSZ) { cnt[t] = 0; rank[t] = 0; }
    if (t == 0) spillN_s = *spillCnt;
    __syncthreads();

    for (int e = base + t; e < end; e += 256)
        atomicAdd(&cnt[(stg[e] >> 17) & 63], 1);
    __syncthreads();

    if (t < BSZ) sc[t] = cnt[t];
    __syncthreads();
    for (int off = 1; off < BSZ; off <<= 1) {
        int x = 0;
        if (t < BSZ && t >= off) x = sc[t - off];
        __syncthreads();
        if (t < BSZ) sc[t] += x;
        __syncthreads();
    }
    if (t < BSZ) st2[t] = sc[t] - cnt[t];
    __syncthreads();

    for (int e = base + t; e < end; e += 256) {
        int v = stg[e];
        int nl = (v >> 17) & 63;
        int r = atomicAdd(&rank[nl], 1);
        sidx[st2[nl] + r] = v & 0x1FFFF;
    }
    __syncthreads();

    const int w = t >> 6, lane = t & 63;
    const int part = lane & 7;     // 8 lanes x 16B cover one 128B row
    const int slot = lane >> 3;    // 8 rows in flight
    const unsigned char* h8p = h8 + part * 16;
    const int spillN = spillN_s;

#define ACCUM16(V) { \
        f32x2 a_; \
        a_ = __builtin_amdgcn_cvt_pk_f32_fp8((V).x, false); s01[0] += a_; \
        a_ = __builtin_amdgcn_cvt_pk_f32_fp8((V).x, true);  s01[1] += a_; \
        a_ = __builtin_amdgcn_cvt_pk_f32_fp8((V).y, false); s01[2] += a_; \
        a_ = __builtin_amdgcn_cvt_pk_f32_fp8((V).y, true);  s01[3] += a_; \
        a_ = __builtin_amdgcn_cvt_pk_f32_fp8((V).z, false); s01[4] += a_; \
        a_ = __builtin_amdgcn_cvt_pk_f32_fp8((V).z, true);  s01[5] += a_; \
        a_ = __builtin_amdgcn_cvt_pk_f32_fp8((V).w, false); s01[6] += a_; \
        a_ = __builtin_amdgcn_cvt_pk_f32_fp8((V).w, true);  s01[7] += a_; }

    for (int k = 0; k < 16; ++k) {
        const int nl = w * 16 + k;
        const int node = node0 + nl;
        if (node >= N) break;
        const int mst = st2[nl];
        const int m   = cnt[nl];

        f32x2 s01[8];
#pragma unroll
        for (int j = 0; j < 8; ++j) s01[j] = (f32x2){0.f, 0.f};

        // pipelined: 8 rows in flight per single uint4 load
        int i = 0;
        bool has = (8 <= m);
        int c0 = 0;
        if (has) c0 = sidx[mst + slot];
        while (has) {
            const bool hn = (i + 16 <= m);
            int n0 = 0;
            if (hn) n0 = sidx[mst + i + 8 + slot];
            const uint4 v = *reinterpret_cast<const uint4*>(h8p + (size_t)c0 * D);
            ACCUM16(v);
            c0 = n0; i += 8; has = hn;
        }
        // tail (< 8 rows)
        if (i + slot < m) {
            const uint4 v = *reinterpret_cast<const uint4*>(
                h8p + (size_t)sidx[mst + i + slot] * D);
            ACCUM16(v);
        }

        int deg = m;
        if (spillN) {      // ~never taken; correctness fallback
            for (int q = 0; q < spillN; ++q) {
                int2 e = spill[q];
                if (e.x == b && ((e.y >> 17) & 63) == nl) {
                    if (slot == 0) {
                        const uint4 v = *reinterpret_cast<const uint4*>(
                            h8p + (size_t)(e.y & 0x1FFFF) * D);
                        ACCUM16(v);
                    }
                    ++deg;
                }
            }
        }

        float s[16];
#pragma unroll
        for (int j = 0; j < 8; ++j) { s[2 * j] = s01[j][0]; s[2 * j + 1] = s01[j][1]; }
#pragma unroll
        for (int j = 0; j < 16; ++j) {
            s[j] += __shfl_xor(s[j], 8);
            s[j] += __shfl_xor(s[j], 16);
            s[j] += __shfl_xor(s[j], 32);
        }
        if (slot == 0) {
            const float scale = 1.0f / fmaxf((float)deg, 1.0f);
            short8 o0, o1;
#pragma unroll
            for (int j = 0; j < 8; ++j) {
                o0[j] = (short)f2b(s[j] * scale);
                o1[j] = (short)f2b(s[8 + j] * scale);
            }
            unsigned short* op = acc + (size_t)node * D + part * 16;
            *reinterpret_cast<short8*>(op) = o0;
            *reinterpret_cast<short8*>(op + 8) = o1;
        }
    }
#undef ACCUM16
}

// ---------------------------------------------------------------------------
// GEMM (fused): both output types in one launch, branch on block range.
// out[N,128] = A0@W0 + A1@W1 [+ A2@W2] + bias; W* fragment-linear bf16.
// ---------------------------------------------------------------------------
__global__ __launch_bounds__(512) void gemm_all(
    const unsigned short* __restrict__ hbU,
    const unsigned short* __restrict__ accUU, const unsigned short* __restrict__ accIU,
    const short8* __restrict__ WfU0, const short8* __restrict__ WfU1,
    const short8* __restrict__ WfU2, const float* __restrict__ bsum,
    const unsigned short* __restrict__ hbI, const unsigned short* __restrict__ accUI,
    const short8* __restrict__ WfI0, const short8* __restrict__ WfI1,
    const float* __restrict__ b_ui,
    float* __restrict__ outU, float* __restrict__ outI,
    int NU, int NI, int nBlkU)
{
    __shared__ short8 lds[2048];     // 32 KB: one fragment-linear W
    const int t = threadIdx.x;
    const int w = t >> 6, l = t & 63;

    const unsigned short *A0, *A1, *A2;
    const short8 *W0, *W1, *W2;
    const float* bias; float* out; int N; int blk;
    if (blockIdx.x < nBlkU) {
        blk = blockIdx.x;
        A0 = hbU; A1 = accUU; A2 = accIU;
        W0 = WfU0; W1 = WfU1; W2 = WfU2;
        bias = bsum; out = outU; N = NU;
    } else {
        blk = blockIdx.x - nBlkU;
        A0 = hbI; A1 = accUI; A2 = nullptr;
        W0 = WfI0; W1 = WfI1; W2 = nullptr;
        bias = b_ui; out = outI; N = NI;
    }

    const int row0 = blk * 128 + w * 16;
    const int arow = row0 + (l & 15);

    f32x4 acc[8];
#pragma unroll
    for (int c = 0; c < 8; ++c) acc[c] = (f32x4){0.f, 0.f, 0.f, 0.f};

    const unsigned short* As[3] = {A0, A1, A2};
    const short8* Wfs[3] = {W0, W1, W2};
    const int nsrc = (A2 != nullptr) ? 3 : 2;

    for (int sI = 0; sI < nsrc; ++sI) {
        __syncthreads();
        const short8* Wg = Wfs[sI];
#pragma unroll
        for (int i = 0; i < 4; ++i) lds[t + i * 512] = Wg[t + i * 512];
        __syncthreads();

        const unsigned short* A = As[sI];
        short8 af[4];
        if (arow < N) {
            const unsigned short* base = A + (size_t)arow * D + ((l >> 4) << 3);
#pragma unroll
            for (int kc = 0; kc < 4; ++kc)
                af[kc] = *reinterpret_cast<const short8*>(base + kc * 32);
        } else {
            short8 z = {0, 0, 0, 0, 0, 0, 0, 0};
#pragma unroll
            for (int kc = 0; kc < 4; ++kc) af[kc] = z;
        }
#pragma unroll
        for (int kc = 0; kc < 4; ++kc)
#pragma unroll
            for (int c = 0; c < 8; ++c)
                acc[c] = __builtin_amdgcn_mfma_f32_16x16x32_bf16(
                    af[kc], lds[(c * 4 + kc) * 64 + l], acc[c], 0, 0, 0);
    }

    const int col = l & 15;
#pragma unroll
    for (int c = 0; c < 8; ++c) {
        float bv = bias[c * 16 + col];
#pragma unroll
        for (int r = 0; r < 4; ++r) {
            int row = row0 + ((l >> 4) << 2) + r;
            if (row < N)
                out[(size_t)row * D + c * 16 + col] = acc[c][r] + bv;
        }
    }
}

// ---------------------------------------------------------------------------
extern "C" void kernel_launch(void* const* d_in, const int* in_sizes, int n_in,
                              void* d_out, int out_size, void* d_ws, size_t ws_size,
                              hipStream_t stream)
{
    const float* h_user    = (const float*)d_in[0];
    const float* h_item    = (const float*)d_in[1];
    const float* Wself_uu  = (const float*)d_in[2];
    const float* Wneigh_uu = (const float*)d_in[3];
    const float* b_uu      = (const float*)d_in[4];
    const float* Wself_ui  = (const float*)d_in[5];
    const float* Wneigh_ui = (const float*)d_in[6];
    const float* b_ui      = (const float*)d_in[7];
    const float* Wself_iu  = (const float*)d_in[8];
    const float* Wneigh_iu = (const float*)d_in[9];
    const float* b_iu      = (const float*)d_in[10];
    const int* e_uu_src    = (const int*)d_in[11];
    const int* e_uu_dst    = (const int*)d_in[12];
    const int* e_ui_src    = (const int*)d_in[13];
    const int* e_ui_dst    = (const int*)d_in[14];
    const int* e_iu_src    = (const int*)d_in[15];
    const int* e_iu_dst    = (const int*)d_in[16];

    const int NU = in_sizes[0] / D;
    const int NI = in_sizes[1] / D;
    const int E_uu = in_sizes[11];
    const int E_ui = in_sizes[13];
    const int E_iu = in_sizes[15];

    const int NB0 = (NU + BSZ - 1) / BSZ;   // uu (dst=user)
    const int NB1 = (NU + BSZ - 1) / BSZ;   // iu (dst=user)
    const int NB2 = (NI + BSZ - 1) / BSZ;   // ui (dst=item)
    const int NBT = NB0 + NB1 + NB2;

    // ---- workspace carve-up (16B-aligned chunks) ----
    char* p = (char*)d_ws;
    unsigned short* hbU   = (unsigned short*)p; p += (size_t)NU * D * 2;
    unsigned short* hbI   = (unsigned short*)p; p += (size_t)NI * D * 2;
    unsigned char* h8U    = (unsigned char*)p; p += (size_t)NU * D;
    unsigned char* h8I    = (unsigned char*)p; p += (size_t)NI * D;
    unsigned short* accUU = (unsigned short*)p; p += (size_t)NU * D * 2;
    unsigned short* accIU = (unsigned short*)p; p += (size_t)NU * D * 2;
    unsigned short* accUI = (unsigned short*)p; p += (size_t)NI * D * 2;
    short8* WfU0 = (short8*)p; p += 32768;
    short8* WfU1 = (short8*)p; p += 32768;
    short8* WfU2 = (short8*)p; p += 32768;
    short8* WfI0 = (short8*)p; p += 32768;
    short8* WfI1 = (short8*)p; p += 32768;
    float* bsum  = (float*)p;  p += 512;
    int* cursors = (int*)p; p += (size_t)((NBT + 3) & ~3) * 4;
    int* spillCnt = (int*)p; p += 16;
    int2* spill  = (int2*)p; p += (size_t)SPILL_MAX * 8;
    int* stg     = (int*)p; p += (size_t)NBT * CAPG * 4;

    // zero cursors + spill counter (contiguous, ~9.5 KB)
    hipMemsetAsync(cursors, 0, ((size_t)((NBT + 3) & ~3) + 16) * sizeof(int), stream);

    const int nU8 = NU * D / 8, nI8 = NI * D / 8;
    const int nConvH = (nU8 + nI8 + 1023) / 1024;
    const int nblk0 = (E_uu + CHUNK - 1) / CHUNK;
    const int nblk1 = (E_iu + CHUNK - 1) / CHUNK;
    const int nblk2 = (E_ui + CHUNK - 1) / CHUNK;
    const int nblkS = nblk0 + nblk1 + nblk2;

    prep_scatter<<<nblkS + nConvH + 11, 1024, 0, stream>>>(
        e_uu_src, e_uu_dst, E_uu,
        e_iu_src, e_iu_dst, E_iu,
        e_ui_src, e_ui_dst, E_ui,
        NB0, NB1, cursors, stg, spill, spillCnt, nblk0, nblk1, nblkS,
        h_user, h_item, nU8, nI8, hbU, hbI, h8U, h8I,
        Wself_uu, Wself_iu, Wneigh_uu, Wneigh_iu, Wself_ui, Wneigh_ui,
        WfU0, WfU1, WfU2, WfI0, WfI1,
        b_uu, b_iu, bsum, nConvH);

    gather_bucket<<<NBT, 256, 0, stream>>>(
        h8U, h8I, stg, cursors, spill, spillCnt,
        accUU, accIU, accUI, NB0, NB1, NU, NI);

    float* out_user = (float*)d_out;
    float* out_item = out_user + (size_t)NU * D;
    const int nBlkU = (NU + 127) / 128, nBlkI = (NI + 127) / 128;

    gemm_all<<<nBlkU + nBlkI, 512, 0, stream>>>(
        hbU, accUU, accIU, WfU0, WfU1, WfU2, bsum,
        hbI, accUI, WfI0, WfI1, b_ui,
        out_user, out_item, NU, NI, nBlkU);
}

// Round 20
// 119.262 us; speedup vs baseline: 1.4016x; 1.4016x over previous
//
#include <hip/hip_runtime.h>

#define D 128
#define BSZ 64             // dst nodes per bucket
#define CHUNK 8192         // edges per scatter block
#define CAPG 1536          // staging slots per bucket (mean ~767, sigma ~28)
#define SPILL_MAX 65536

typedef __attribute__((ext_vector_type(8))) short short8;
typedef __attribute__((ext_vector_type(4))) float f32x4;
typedef __attribute__((ext_vector_type(2))) float f32x2;

__device__ inline unsigned short f2b(float f) {
    union { float f; unsigned int u; } x; x.f = f;
    unsigned int r = x.u + 0x7FFFu + ((x.u >> 16) & 1u);
    return (unsigned short)(r >> 16);
}

// ---------------------------------------------------------------------------
// prep_scatter (fused, 1024-thread blocks, cursors pre-zeroed by memset):
//   [0, nblkS)            bucket scatter, register-staged edges, 16 waves/blk
//   [nblkS, +nConvH)      h fp32 -> bf16 (GEMM) AND fp8-e4m3 (gather)
//   [.., +10)             W fragment packing
//   [last]                bias sum
// ---------------------------------------------------------------------------
__global__ __launch_bounds__(1024) void prep_scatter(
    const int* __restrict__ s_uu, const int* __restrict__ d_uu, int E_uu,
    const int* __restrict__ s_iu, const int* __restrict__ d_iu, int E_iu,
    const int* __restrict__ s_ui, const int* __restrict__ d_ui, int E_ui,
    int NB0, int NB1,
    int* __restrict__ cursors, int* __restrict__ stg,
    int2* __restrict__ spill, int* __restrict__ spillCnt,
    int nblk0, int nblk1, int nblkS,
    const float* __restrict__ hU, const float* __restrict__ hI,
    int nU8, int nI8,
    unsigned short* __restrict__ hbU, unsigned short* __restrict__ hbI,
    unsigned char* __restrict__ h8U, unsigned char* __restrict__ h8I,
    const float* __restrict__ Wself_uu, const float* __restrict__ Wself_iu,
    const float* __restrict__ Wneigh_uu, const float* __restrict__ Wneigh_iu,
    const float* __restrict__ Wself_ui, const float* __restrict__ Wneigh_ui,
    short8* __restrict__ WfU0, short8* __restrict__ WfU1, short8* __restrict__ WfU2,
    short8* __restrict__ WfI0, short8* __restrict__ WfI1,
    const float* __restrict__ b_uu, const float* __restrict__ b_iu,
    float* __restrict__ bsum, int nConvH)
{
    __shared__ int hist[1024];
    __shared__ int bbase[1024];
    const int t = threadIdx.x;

    if (blockIdx.x >= nblkS) {
        const int cb = blockIdx.x - nblkS;
        if (cb < nConvH) {
            // ---- h conversion: 8 floats per thread ----
            int g = cb * 1024 + t;
            const float* src; unsigned short* dst; unsigned char* dst8;
            if (g < nU8) {
                src = hU + (size_t)g * 8; dst = hbU + (size_t)g * 8;
                dst8 = h8U + (size_t)g * 8;
            } else {
                g -= nU8;
                if (g >= nI8) return;
                src = hI + (size_t)g * 8; dst = hbI + (size_t)g * 8;
                dst8 = h8I + (size_t)g * 8;
            }
            const float4 a = *reinterpret_cast<const float4*>(src);
            const float4 c = *reinterpret_cast<const float4*>(src + 4);
            short8 o;
            o[0] = (short)f2b(a.x); o[1] = (short)f2b(a.y);
            o[2] = (short)f2b(a.z); o[3] = (short)f2b(a.w);
            o[4] = (short)f2b(c.x); o[5] = (short)f2b(c.y);
            o[6] = (short)f2b(c.z); o[7] = (short)f2b(c.w);
            *reinterpret_cast<short8*>(dst) = o;
            unsigned int p0 = __builtin_amdgcn_cvt_pk_fp8_f32(a.x, a.y, 0, false);
            p0 = __builtin_amdgcn_cvt_pk_fp8_f32(a.z, a.w, p0, true);
            unsigned int p1 = __builtin_amdgcn_cvt_pk_fp8_f32(c.x, c.y, 0, false);
            p1 = __builtin_amdgcn_cvt_pk_fp8_f32(c.z, c.w, p1, true);
            *reinterpret_cast<uint2*>(dst8) = make_uint2(p0, p1);
            return;
        }
        const int wb = cb - nConvH;
        if (wb < 10) {
            // ---- W fragment packing: weight wb>>1, half wb&1 ----
            const float* Wa; const float* Wb = nullptr; short8* Wf;
            switch (wb >> 1) {
                case 0: Wa = Wself_uu; Wb = Wself_iu; Wf = WfU0; break;
                case 1: Wa = Wneigh_uu; Wf = WfU1; break;
                case 2: Wa = Wneigh_iu; Wf = WfU2; break;
                case 3: Wa = Wself_ui;  Wf = WfI0; break;
                default: Wa = Wneigh_ui; Wf = WfI1; break;
            }
            int t2 = (wb & 1) * 1024 + t;           // 0..2047
            int c  = t2 >> 8;
            int kc = (t2 >> 6) & 3;
            int l  = t2 & 63;
            int n  = c * 16 + (l & 15);
            int k0 = kc * 32 + ((l >> 4) << 3);
            short8 o;
#pragma unroll
            for (int j = 0; j < 8; ++j) {
                float v = Wa[(k0 + j) * D + n];
                if (Wb) v += Wb[(k0 + j) * D + n];
                o[j] = (short)f2b(v);
            }
            Wf[t2] = o;
            return;
        }
        if (t < D) bsum[t] = b_uu[t] + b_iu[t];
        return;
    }

    // ---------------- scatter: register-staged, 2 LDS passes ----------------
    const int* src; const int* dst; int E; int relBase; int b0;
    if (blockIdx.x < nblk0) {
        b0 = blockIdx.x; src = s_uu; dst = d_uu; E = E_uu; relBase = 0;
    } else if (blockIdx.x < nblk0 + nblk1) {
        b0 = blockIdx.x - nblk0; src = s_iu; dst = d_iu; E = E_iu; relBase = NB0;
    } else {
        b0 = blockIdx.x - nblk0 - nblk1; src = s_ui; dst = d_ui; E = E_ui;
        relBase = NB0 + NB1;
    }
    const int mye = b0 * CHUNK + t * 8;      // this thread's 8 edges
    const int nv  = min(8, max(0, E - mye)); // valid count

    int ed[8], es[8];
    if (nv == 8) {
        *reinterpret_cast<int4*>(&ed[0]) = *reinterpret_cast<const int4*>(dst + mye);
        *reinterpret_cast<int4*>(&ed[4]) = *reinterpret_cast<const int4*>(dst + mye + 4);
        *reinterpret_cast<int4*>(&es[0]) = *reinterpret_cast<const int4*>(src + mye);
        *reinterpret_cast<int4*>(&es[4]) = *reinterpret_cast<const int4*>(src + mye + 4);
    } else {
        for (int j = 0; j < 8; ++j) {
            ed[j] = (j < nv) ? dst[mye + j] : 0;
            es[j] = (j < nv) ? src[mye + j] : 0;
        }
    }

    hist[t] = 0;
    __syncthreads();

#pragma unroll
    for (int j = 0; j < 8; ++j)
        if (j < nv) atomicAdd(&hist[ed[j] >> 6], 1);
    __syncthreads();

    {
        int c = hist[t];
        bbase[t] = c ? ((relBase + t) * CAPG + atomicAdd(&cursors[relBase + t], c)) : 0;
        hist[t] = 0;    // reuse as rank counter
    }
    __syncthreads();

#pragma unroll
    for (int j = 0; j < 8; ++j) {
        if (j < nv) {
            int dv = ed[j];
            int bkt = dv >> 6;
            int g = relBase + bkt;
            int r = atomicAdd(&hist[bkt], 1);
            int pos = bbase[bkt] + r;
            int packed = (es[j] & 0x1FFFF) | ((dv & 63) << 17);
            if (pos < (g + 1) * CAPG) {
                stg[pos] = packed;
            } else {
                int si = atomicAdd(spillCnt, 1);
                if (si < SPILL_MAX) spill[si] = make_int2(g, packed);
            }
        }
    }
}

// ---------------------------------------------------------------------------
// gather_bucket: one block per 64-node bucket. Counting-sort the ~767-edge
// window into 6KB LDS, then per-node gather: 16 rows per round, all loads
// UNCONDITIONAL via index clamping (min(e, m-1)); out-of-range rows are
// zeroed post-load with cndmask (fp8 0x00 == 0.0). One latency round covers
// deg<=16 (~91% of nodes). fp8 rows (HW cvt), bf16 means. 4 waves x 16 nodes.
// ---------------------------------------------------------------------------
__global__ __launch_bounds__(256) void gather_bucket(
    const unsigned char* __restrict__ h8U, const unsigned char* __restrict__ h8I,
    const int* __restrict__ stg, const int* __restrict__ cursors,
    const int2* __restrict__ spill, const int* __restrict__ spillCnt,
    unsigned short* __restrict__ accUU, unsigned short* __restrict__ accIU,
    unsigned short* __restrict__ accUI,
    int NB0, int NB1, int NU, int NI)
{
    __shared__ int sidx[CAPG];      // 6 KB sorted edge sources
    __shared__ int cnt[BSZ];
    __shared__ int st2[BSZ];
    __shared__ int rank[BSZ];
    __shared__ int sc[BSZ];
    __shared__ int spillN_s;

    const int b = blockIdx.x;
    const unsigned char* h8; unsigned short* acc; int N; int lb;
    if (b < NB0)            { lb = b;             h8 = h8U; acc = accUU; N = NU; }
    else if (b < NB0 + NB1) { lb = b - NB0;       h8 = h8I; acc = accIU; N = NU; }
    else                    { lb = b - NB0 - NB1; h8 = h8U; acc = accUI; N = NI; }

    const int t = threadIdx.x;
    const int node0 = lb * BSZ;
    const int base  = b * CAPG;
    const int end   = base + min(cursors[b], CAPG);

    if (t < BSZ) { cnt[t] = 0; rank[t] = 0; }
    if (t == 0) spillN_s = *spillCnt;
    __syncthreads();

    for (int e = base + t; e < end; e += 256)
        atomicAdd(&cnt[(stg[e] >> 17) & 63], 1);
    __syncthreads();

    if (t < BSZ) sc[t] = cnt[t];
    __syncthreads();
    for (int off = 1; off < BSZ; off <<= 1) {
        int x = 0;
        if (t < BSZ && t >= off) x = sc[t - off];
        __syncthreads();
        if (t < BSZ) sc[t] += x;
        __syncthreads();
    }
    if (t < BSZ) st2[t] = sc[t] - cnt[t];
    __syncthreads();

    for (int e = base + t; e < end; e += 256) {
        int v = stg[e];
        int nl = (v >> 17) & 63;
        int r = atomicAdd(&rank[nl], 1);
        sidx[st2[nl] + r] = v & 0x1FFFF;
    }
    __syncthreads();

    const int w = t >> 6, lane = t & 63;
    const int part = lane & 15, slot = lane >> 4;
    const unsigned char* h8p = h8 + part * 8;
    const int spillN = spillN_s;

#define ACCUM8(V) { \
        f32x2 a0 = __builtin_amdgcn_cvt_pk_f32_fp8((V).x, false); \
        f32x2 a1 = __builtin_amdgcn_cvt_pk_f32_fp8((V).x, true);  \
        f32x2 a2 = __builtin_amdgcn_cvt_pk_f32_fp8((V).y, false); \
        f32x2 a3 = __builtin_amdgcn_cvt_pk_f32_fp8((V).y, true);  \
        s01[0] += a0; s01[1] += a1; s01[2] += a2; s01[3] += a3; }

    for (int k = 0; k < 16; ++k) {
        const int nl = w * 16 + k;
        const int node = node0 + nl;
        if (node >= N) break;
        const int mst = st2[nl];
        const int m   = cnt[nl];

        f32x2 s01[4];
#pragma unroll
        for (int j = 0; j < 4; ++j) s01[j] = (f32x2){0.f, 0.f};

        // 16 rows per round, loads unconditional (indices clamped to m-1),
        // out-of-range values zeroed post-load. One round covers deg<=16.
        const int mm1 = m - 1;
        for (int i = 0; i < m; i += 16) {
            const int e0 = i + slot;
            const int e1 = i + 4 + slot;
            const int e2 = i + 8 + slot;
            const int e3 = i + 12 + slot;
            const int i0 = sidx[mst + min(e0, mm1)];
            const int i1 = sidx[mst + min(e1, mm1)];
            const int i2 = sidx[mst + min(e2, mm1)];
            const int i3 = sidx[mst + min(e3, mm1)];
            uint2 v0 = *reinterpret_cast<const uint2*>(h8p + (size_t)i0 * D);
            uint2 v1 = *reinterpret_cast<const uint2*>(h8p + (size_t)i1 * D);
            uint2 v2 = *reinterpret_cast<const uint2*>(h8p + (size_t)i2 * D);
            uint2 v3 = *reinterpret_cast<const uint2*>(h8p + (size_t)i3 * D);
            v0.x = (e0 <= mm1) ? v0.x : 0u;  v0.y = (e0 <= mm1) ? v0.y : 0u;
            v1.x = (e1 <= mm1) ? v1.x : 0u;  v1.y = (e1 <= mm1) ? v1.y : 0u;
            v2.x = (e2 <= mm1) ? v2.x : 0u;  v2.y = (e2 <= mm1) ? v2.y : 0u;
            v3.x = (e3 <= mm1) ? v3.x : 0u;  v3.y = (e3 <= mm1) ? v3.y : 0u;
            ACCUM8(v0);
            ACCUM8(v1);
            ACCUM8(v2);
            ACCUM8(v3);
        }

        int deg = m;
        if (spillN) {      // ~never taken; correctness fallback
            for (int q = 0; q < spillN; ++q) {
                int2 e = spill[q];
                if (e.x == b && ((e.y >> 17) & 63) == nl) {
                    if (slot == 0) {
                        const uint2 v = *reinterpret_cast<const uint2*>(
                            h8p + (size_t)(e.y & 0x1FFFF) * D);
                        ACCUM8(v);
                    }
                    ++deg;
                }
            }
        }

        float s[8];
#pragma unroll
        for (int j = 0; j < 4; ++j) { s[2 * j] = s01[j][0]; s[2 * j + 1] = s01[j][1]; }
#pragma unroll
        for (int j = 0; j < 8; ++j) {
            s[j] += __shfl_xor(s[j], 16);
            s[j] += __shfl_xor(s[j], 32);
        }
        if (slot == 0) {
            const float scale = 1.0f / fmaxf((float)deg, 1.0f);
            short8 o;
#pragma unroll
            for (int j = 0; j < 8; ++j) o[j] = (short)f2b(s[j] * scale);
            *reinterpret_cast<short8*>(acc + (size_t)node * D + part * 8) = o;
        }
    }
#undef ACCUM8
}

// ---------------------------------------------------------------------------
// GEMM (fused): both output types in one launch, branch on block range.
// out[N,128] = A0@W0 + A1@W1 [+ A2@W2] + bias; W* fragment-linear bf16.
// ---------------------------------------------------------------------------
__global__ __launch_bounds__(512) void gemm_all(
    const unsigned short* __restrict__ hbU,
    const unsigned short* __restrict__ accUU, const unsigned short* __restrict__ accIU,
    const short8* __restrict__ WfU0, const short8* __restrict__ WfU1,
    const short8* __restrict__ WfU2, const float* __restrict__ bsum,
    const unsigned short* __restrict__ hbI, const unsigned short* __restrict__ accUI,
    const short8* __restrict__ WfI0, const short8* __restrict__ WfI1,
    const float* __restrict__ b_ui,
    float* __restrict__ outU, float* __restrict__ outI,
    int NU, int NI, int nBlkU)
{
    __shared__ short8 lds[2048];     // 32 KB: one fragment-linear W
    const int t = threadIdx.x;
    const int w = t >> 6, l = t & 63;

    const unsigned short *A0, *A1, *A2;
    const short8 *W0, *W1, *W2;
    const float* bias; float* out; int N; int blk;
    if (blockIdx.x < nBlkU) {
        blk = blockIdx.x;
        A0 = hbU; A1 = accUU; A2 = accIU;
        W0 = WfU0; W1 = WfU1; W2 = WfU2;
        bias = bsum; out = outU; N = NU;
    } else {
        blk = blockIdx.x - nBlkU;
        A0 = hbI; A1 = accUI; A2 = nullptr;
        W0 = WfI0; W1 = WfI1; W2 = nullptr;
        bias = b_ui; out = outI; N = NI;
    }

    const int row0 = blk * 128 + w * 16;
    const int arow = row0 + (l & 15);

    f32x4 acc[8];
#pragma unroll
    for (int c = 0; c < 8; ++c) acc[c] = (f32x4){0.f, 0.f, 0.f, 0.f};

    const unsigned short* As[3] = {A0, A1, A2};
    const short8* Wfs[3] = {W0, W1, W2};
    const int nsrc = (A2 != nullptr) ? 3 : 2;

    for (int sI = 0; sI < nsrc; ++sI) {
        __syncthreads();
        const short8* Wg = Wfs[sI];
#pragma unroll
        for (int i = 0; i < 4; ++i) lds[t + i * 512] = Wg[t + i * 512];
        __syncthreads();

        const unsigned short* A = As[sI];
        short8 af[4];
        if (arow < N) {
            const unsigned short* base = A + (size_t)arow * D + ((l >> 4) << 3);
#pragma unroll
            for (int kc = 0; kc < 4; ++kc)
                af[kc] = *reinterpret_cast<const short8*>(base + kc * 32);
        } else {
            short8 z = {0, 0, 0, 0, 0, 0, 0, 0};
#pragma unroll
            for (int kc = 0; kc < 4; ++kc) af[kc] = z;
        }
#pragma unroll
        for (int kc = 0; kc < 4; ++kc)
#pragma unroll
            for (int c = 0; c < 8; ++c)
                acc[c] = __builtin_amdgcn_mfma_f32_16x16x32_bf16(
                    af[kc], lds[(c * 4 + kc) * 64 + l], acc[c], 0, 0, 0);
    }

    const int col = l & 15;
#pragma unroll
    for (int c = 0; c < 8; ++c) {
        float bv = bias[c * 16 + col];
#pragma unroll
        for (int r = 0; r < 4; ++r) {
            int row = row0 + ((l >> 4) << 2) + r;
            if (row < N)
                out[(size_t)row * D + c * 16 + col] = acc[c][r] + bv;
        }
    }
}

// ---------------------------------------------------------------------------
extern "C" void kernel_launch(void* const* d_in, const int* in_sizes, int n_in,
                              void* d_out, int out_size, void* d_ws, size_t ws_size,
                              hipStream_t stream)
{
    const float* h_user    = (const float*)d_in[0];
    const float* h_item    = (const float*)d_in[1];
    const float* Wself_uu  = (const float*)d_in[2];
    const float* Wneigh_uu = (const float*)d_in[3];
    const float* b_uu      = (const float*)d_in[4];
    const float* Wself_ui  = (const float*)d_in[5];
    const float* Wneigh_ui = (const float*)d_in[6];
    const float* b_ui      = (const float*)d_in[7];
    const float* Wself_iu  = (const float*)d_in[8];
    const float* Wneigh_iu = (const float*)d_in[9];
    const float* b_iu      = (const float*)d_in[10];
    const int* e_uu_src    = (const int*)d_in[11];
    const int* e_uu_dst    = (const int*)d_in[12];
    const int* e_ui_src    = (const int*)d_in[13];
    const int* e_ui_dst    = (const int*)d_in[14];
    const int* e_iu_src    = (const int*)d_in[15];
    const int* e_iu_dst    = (const int*)d_in[16];

    const int NU = in_sizes[0] / D;
    const int NI = in_sizes[1] / D;
    const int E_uu = in_sizes[11];
    const int E_ui = in_sizes[13];
    const int E_iu = in_sizes[15];

    const int NB0 = (NU + BSZ - 1) / BSZ;   // uu (dst=user)
    const int NB1 = (NU + BSZ - 1) / BSZ;   // iu (dst=user)
    const int NB2 = (NI + BSZ - 1) / BSZ;   // ui (dst=item)
    const int NBT = NB0 + NB1 + NB2;

    // ---- workspace carve-up (16B-aligned chunks) ----
    char* p = (char*)d_ws;
    unsigned short* hbU   = (unsigned short*)p; p += (size_t)NU * D * 2;
    unsigned short* hbI   = (unsigned short*)p; p += (size_t)NI * D * 2;
    unsigned char* h8U    = (unsigned char*)p; p += (size_t)NU * D;
    unsigned char* h8I    = (unsigned char*)p; p += (size_t)NI * D;
    unsigned short* accUU = (unsigned short*)p; p += (size_t)NU * D * 2;
    unsigned short* accIU = (unsigned short*)p; p += (size_t)NU * D * 2;
    unsigned short* accUI = (unsigned short*)p; p += (size_t)NI * D * 2;
    short8* WfU0 = (short8*)p; p += 32768;
    short8* WfU1 = (short8*)p; p += 32768;
    short8* WfU2 = (short8*)p; p += 32768;
    short8* WfI0 = (short8*)p; p += 32768;
    short8* WfI1 = (short8*)p; p += 32768;
    float* bsum  = (float*)p;  p += 512;
    int* cursors = (int*)p; p += (size_t)((NBT + 3) & ~3) * 4;
    int* spillCnt = (int*)p; p += 16;
    int2* spill  = (int2*)p; p += (size_t)SPILL_MAX * 8;
    int* stg     = (int*)p; p += (size_t)NBT * CAPG * 4;

    // zero cursors + spill counter (contiguous, ~9.5 KB)
    hipMemsetAsync(cursors, 0, ((size_t)((NBT + 3) & ~3) + 16) * sizeof(int), stream);

    const int nU8 = NU * D / 8, nI8 = NI * D / 8;
    const int nConvH = (nU8 + nI8 + 1023) / 1024;
    const int nblk0 = (E_uu + CHUNK - 1) / CHUNK;
    const int nblk1 = (E_iu + CHUNK - 1) / CHUNK;
    const int nblk2 = (E_ui + CHUNK - 1) / CHUNK;
    const int nblkS = nblk0 + nblk1 + nblk2;

    prep_scatter<<<nblkS + nConvH + 11, 1024, 0, stream>>>(
        e_uu_src, e_uu_dst, E_uu,
        e_iu_src, e_iu_dst, E_iu,
        e_ui_src, e_ui_dst, E_ui,
        NB0, NB1, cursors, stg, spill, spillCnt, nblk0, nblk1, nblkS,
        h_user, h_item, nU8, nI8, hbU, hbI, h8U, h8I,
        Wself_uu, Wself_iu, Wneigh_uu, Wneigh_iu, Wself_ui, Wneigh_ui,
        WfU0, WfU1, WfU2, WfI0, WfI1,
        b_uu, b_iu, bsum, nConvH);

    gather_bucket<<<NBT, 256, 0, stream>>>(
        h8U, h8I, stg, cursors, spill, spillCnt,
        accUU, accIU, accUI, NB0, NB1, NU, NI);

    float* out_user = (float*)d_out;
    float* out_item = out_user + (size_t)NU * D;
    const int nBlkU = (NU + 127) / 128, nBlkI = (NI + 127) / 128;

    gemm_all<<<nBlkU + nBlkI, 512, 0, stream>>>(
        hbU, accUU, accIU, WfU0, WfU1, WfU2, bsum,
        hbI, accUI, WfI0, WfI1, b_ui,
        out_user, out_item, NU, NI, nBlkU);
}

// Round 21
// 119.071 us; speedup vs baseline: 1.4039x; 1.0016x over previous
//
#include <hip/hip_runtime.h>

#define D 128
#define BSZ 64             // dst nodes per bucket
#define CHUNK 8192         // edges per scatter block
#define CAPG 1536          // staging slots per bucket (mean ~767, sigma ~28)
#define SPILL_MAX 65536

typedef __attribute__((ext_vector_type(8))) short short8;
typedef __attribute__((ext_vector_type(4))) float f32x4;
typedef __attribute__((ext_vector_type(2))) float f32x2;

__device__ inline unsigned short f2b(float f) {
    union { float f; unsigned int u; } x; x.f = f;
    unsigned int r = x.u + 0x7FFFu + ((x.u >> 16) & 1u);
    return (unsigned short)(r >> 16);
}

// ---------------------------------------------------------------------------
// prep_scatter (fused, 1024-thread blocks, cursors pre-zeroed by memset):
//   [0, nblkS)            bucket scatter, register-staged edges, 16 waves/blk
//   [nblkS, +nConvH)      h fp32 -> bf16 (GEMM) AND fp8-e4m3 (gather)
//   [.., +10)             W fragment packing
//   [last]                bias sum
// ---------------------------------------------------------------------------
__global__ __launch_bounds__(1024) void prep_scatter(
    const int* __restrict__ s_uu, const int* __restrict__ d_uu, int E_uu,
    const int* __restrict__ s_iu, const int* __restrict__ d_iu, int E_iu,
    const int* __restrict__ s_ui, const int* __restrict__ d_ui, int E_ui,
    int NB0, int NB1,
    int* __restrict__ cursors, int* __restrict__ stg,
    int2* __restrict__ spill, int* __restrict__ spillCnt,
    int nblk0, int nblk1, int nblkS,
    const float* __restrict__ hU, const float* __restrict__ hI,
    int nU8, int nI8,
    unsigned short* __restrict__ hbU, unsigned short* __restrict__ hbI,
    unsigned char* __restrict__ h8U, unsigned char* __restrict__ h8I,
    const float* __restrict__ Wself_uu, const float* __restrict__ Wself_iu,
    const float* __restrict__ Wneigh_uu, const float* __restrict__ Wneigh_iu,
    const float* __restrict__ Wself_ui, const float* __restrict__ Wneigh_ui,
    short8* __restrict__ WfU0, short8* __restrict__ WfU1, short8* __restrict__ WfU2,
    short8* __restrict__ WfI0, short8* __restrict__ WfI1,
    const float* __restrict__ b_uu, const float* __restrict__ b_iu,
    float* __restrict__ bsum, int nConvH)
{
    __shared__ int hist[1024];
    __shared__ int bbase[1024];
    const int t = threadIdx.x;

    if (blockIdx.x >= nblkS) {
        const int cb = blockIdx.x - nblkS;
        if (cb < nConvH) {
            // ---- h conversion: 8 floats per thread ----
            int g = cb * 1024 + t;
            const float* src; unsigned short* dst; unsigned char* dst8;
            if (g < nU8) {
                src = hU + (size_t)g * 8; dst = hbU + (size_t)g * 8;
                dst8 = h8U + (size_t)g * 8;
            } else {
                g -= nU8;
                if (g >= nI8) return;
                src = hI + (size_t)g * 8; dst = hbI + (size_t)g * 8;
                dst8 = h8I + (size_t)g * 8;
            }
            const float4 a = *reinterpret_cast<const float4*>(src);
            const float4 c = *reinterpret_cast<const float4*>(src + 4);
            short8 o;
            o[0] = (short)f2b(a.x); o[1] = (short)f2b(a.y);
            o[2] = (short)f2b(a.z); o[3] = (short)f2b(a.w);
            o[4] = (short)f2b(c.x); o[5] = (short)f2b(c.y);
            o[6] = (short)f2b(c.z); o[7] = (short)f2b(c.w);
            *reinterpret_cast<short8*>(dst) = o;
            unsigned int p0 = __builtin_amdgcn_cvt_pk_fp8_f32(a.x, a.y, 0, false);
            p0 = __builtin_amdgcn_cvt_pk_fp8_f32(a.z, a.w, p0, true);
            unsigned int p1 = __builtin_amdgcn_cvt_pk_fp8_f32(c.x, c.y, 0, false);
            p1 = __builtin_amdgcn_cvt_pk_fp8_f32(c.z, c.w, p1, true);
            *reinterpret_cast<uint2*>(dst8) = make_uint2(p0, p1);
            return;
        }
        const int wb = cb - nConvH;
        if (wb < 10) {
            // ---- W fragment packing: weight wb>>1, half wb&1 ----
            const float* Wa; const float* Wb = nullptr; short8* Wf;
            switch (wb >> 1) {
                case 0: Wa = Wself_uu; Wb = Wself_iu; Wf = WfU0; break;
                case 1: Wa = Wneigh_uu; Wf = WfU1; break;
                case 2: Wa = Wneigh_iu; Wf = WfU2; break;
                case 3: Wa = Wself_ui;  Wf = WfI0; break;
                default: Wa = Wneigh_ui; Wf = WfI1; break;
            }
            int t2 = (wb & 1) * 1024 + t;           // 0..2047
            int c  = t2 >> 8;
            int kc = (t2 >> 6) & 3;
            int l  = t2 & 63;
            int n  = c * 16 + (l & 15);
            int k0 = kc * 32 + ((l >> 4) << 3);
            short8 o;
#pragma unroll
            for (int j = 0; j < 8; ++j) {
                float v = Wa[(k0 + j) * D + n];
                if (Wb) v += Wb[(k0 + j) * D + n];
                o[j] = (short)f2b(v);
            }
            Wf[t2] = o;
            return;
        }
        if (t < D) bsum[t] = b_uu[t] + b_iu[t];
        return;
    }

    // ---------------- scatter: register-staged, 2 LDS passes ----------------
    const int* src; const int* dst; int E; int relBase; int b0;
    if (blockIdx.x < nblk0) {
        b0 = blockIdx.x; src = s_uu; dst = d_uu; E = E_uu; relBase = 0;
    } else if (blockIdx.x < nblk0 + nblk1) {
        b0 = blockIdx.x - nblk0; src = s_iu; dst = d_iu; E = E_iu; relBase = NB0;
    } else {
        b0 = blockIdx.x - nblk0 - nblk1; src = s_ui; dst = d_ui; E = E_ui;
        relBase = NB0 + NB1;
    }
    const int mye = b0 * CHUNK + t * 8;      // this thread's 8 edges
    const int nv  = min(8, max(0, E - mye)); // valid count

    int ed[8], es[8];
    if (nv == 8) {
        *reinterpret_cast<int4*>(&ed[0]) = *reinterpret_cast<const int4*>(dst + mye);
        *reinterpret_cast<int4*>(&ed[4]) = *reinterpret_cast<const int4*>(dst + mye + 4);
        *reinterpret_cast<int4*>(&es[0]) = *reinterpret_cast<const int4*>(src + mye);
        *reinterpret_cast<int4*>(&es[4]) = *reinterpret_cast<const int4*>(src + mye + 4);
    } else {
        for (int j = 0; j < 8; ++j) {
            ed[j] = (j < nv) ? dst[mye + j] : 0;
            es[j] = (j < nv) ? src[mye + j] : 0;
        }
    }

    hist[t] = 0;
    __syncthreads();

#pragma unroll
    for (int j = 0; j < 8; ++j)
        if (j < nv) atomicAdd(&hist[ed[j] >> 6], 1);
    __syncthreads();

    {
        int c = hist[t];
        bbase[t] = c ? ((relBase + t) * CAPG + atomicAdd(&cursors[relBase + t], c)) : 0;
        hist[t] = 0;    // reuse as rank counter
    }
    __syncthreads();

#pragma unroll
    for (int j = 0; j < 8; ++j) {
        if (j < nv) {
            int dv = ed[j];
            int bkt = dv >> 6;
            int g = relBase + bkt;
            int r = atomicAdd(&hist[bkt], 1);
            int pos = bbase[bkt] + r;
            int packed = (es[j] & 0x1FFFF) | ((dv & 63) << 17);
            if (pos < (g + 1) * CAPG) {
                stg[pos] = packed;
            } else {
                int si = atomicAdd(spillCnt, 1);
                if (si < SPILL_MAX) spill[si] = make_int2(g, packed);
            }
        }
    }
}

// ---------------------------------------------------------------------------
// gather_bucket: one block per 64-node bucket. Counting-sort the ~767-edge
// window into 6KB LDS, then a per-node gather SOFTWARE-PIPELINED ACROSS
// NODES: node k+1's 4 clamped (unconditional) loads are issued before node
// k's accumulate/reduce, so the ~600cy load round hides under the previous
// node's VALU. Out-of-range rows zeroed post-load (fp8 0x00 == 0.0).
// deg>16 overflow rounds are a rare uniform serial path. 4 waves x 16 nodes.
// ---------------------------------------------------------------------------
__global__ __launch_bounds__(256) void gather_bucket(
    const unsigned char* __restrict__ h8U, const unsigned char* __restrict__ h8I,
    const int* __restrict__ stg, const int* __restrict__ cursors,
    const int2* __restrict__ spill, const int* __restrict__ spillCnt,
    unsigned short* __restrict__ accUU, unsigned short* __restrict__ accIU,
    unsigned short* __restrict__ accUI,
    int NB0, int NB1, int NU, int NI)
{
    __shared__ int sidx[CAPG];      // 6 KB sorted edge sources
    __shared__ int cnt[BSZ];
    __shared__ int st2[BSZ];
    __shared__ int rank[BSZ];
    __shared__ int sc[BSZ];
    __shared__ int spillN_s;

    const int b = blockIdx.x;
    const unsigned char* h8; unsigned short* acc; int N; int lb;
    if (b < NB0)            { lb = b;             h8 = h8U; acc = accUU; N = NU; }
    else if (b < NB0 + NB1) { lb = b - NB0;       h8 = h8I; acc = accIU; N = NU; }
    else                    { lb = b - NB0 - NB1; h8 = h8U; acc = accUI; N = NI; }

    const int t = threadIdx.x;
    const int node0 = lb * BSZ;
    const int base  = b * CAPG;
    const int end   = base + min(cursors[b], CAPG);

    if (t < BSZ) { cnt[t] = 0; rank[t] = 0; }
    if (t == 0) spillN_s = *spillCnt;
    __syncthreads();

    for (int e = base + t; e < end; e += 256)
        atomicAdd(&cnt[(stg[e] >> 17) & 63], 1);
    __syncthreads();

    if (t < BSZ) sc[t] = cnt[t];
    __syncthreads();
    for (int off = 1; off < BSZ; off <<= 1) {
        int x = 0;
        if (t < BSZ && t >= off) x = sc[t - off];
        __syncthreads();
        if (t < BSZ) sc[t] += x;
        __syncthreads();
    }
    if (t < BSZ) st2[t] = sc[t] - cnt[t];
    __syncthreads();

    for (int e = base + t; e < end; e += 256) {
        int v = stg[e];
        int nl = (v >> 17) & 63;
        int r = atomicAdd(&rank[nl], 1);
        sidx[st2[nl] + r] = v & 0x1FFFF;
    }
    __syncthreads();

    const int w = t >> 6, lane = t & 63;
    const int part = lane & 15, slot = lane >> 4;
    const unsigned char* h8p = h8 + part * 8;
    const int spillN = spillN_s;
    const int wbase = w * 16;
    const int nk = min(16, max(0, N - node0 - wbase));

#define ACCUM8(V) { \
        f32x2 a0_ = __builtin_amdgcn_cvt_pk_f32_fp8((V).x, false); \
        f32x2 a1_ = __builtin_amdgcn_cvt_pk_f32_fp8((V).x, true);  \
        f32x2 a2_ = __builtin_amdgcn_cvt_pk_f32_fp8((V).y, false); \
        f32x2 a3_ = __builtin_amdgcn_cvt_pk_f32_fp8((V).y, true);  \
        s01[0] += a0_; s01[1] += a1_; s01[2] += a2_; s01[3] += a3_; }

// Issue node KK's 4 clamped loads (unconditional; indices clamped into range)
#define ISSUE(KK, V0, V1, V2, V3, MM, MST) { \
        const int nl_ = wbase + (KK); \
        MM  = cnt[nl_]; \
        MST = st2[nl_]; \
        const int mm1_ = MM - 1; \
        const int i0_ = sidx[MST + max(0, min(slot,      mm1_))]; \
        const int i1_ = sidx[MST + max(0, min(4 + slot,  mm1_))]; \
        const int i2_ = sidx[MST + max(0, min(8 + slot,  mm1_))]; \
        const int i3_ = sidx[MST + max(0, min(12 + slot, mm1_))]; \
        V0 = *reinterpret_cast<const uint2*>(h8p + (size_t)i0_ * D); \
        V1 = *reinterpret_cast<const uint2*>(h8p + (size_t)i1_ * D); \
        V2 = *reinterpret_cast<const uint2*>(h8p + (size_t)i2_ * D); \
        V3 = *reinterpret_cast<const uint2*>(h8p + (size_t)i3_ * D); }

    uint2 pA0, pA1, pA2, pA3; int mA = 0, stA = 0;
    if (nk > 0) ISSUE(0, pA0, pA1, pA2, pA3, mA, stA);

    for (int k = 0; k < nk; ++k) {
        // prefetch node k+1 (wave-uniform guard: no exec-mask churn on loads)
        uint2 pB0, pB1, pB2, pB3; int mB = 0, stB = 0;
        if (k + 1 < nk) ISSUE(k + 1, pB0, pB1, pB2, pB3, mB, stB);

        const int nl = wbase + k;
        const int node = node0 + nl;
        const int m = mA, mst = stA;
        const int mm1 = m - 1;

        f32x2 s01[4];
#pragma unroll
        for (int j = 0; j < 4; ++j) s01[j] = (f32x2){0.f, 0.f};

        // zero out-of-range rows, then accumulate the 16 in-flight rows
        uint2 v0 = pA0, v1 = pA1, v2 = pA2, v3 = pA3;
        v0.x = (slot      <= mm1) ? v0.x : 0u;  v0.y = (slot      <= mm1) ? v0.y : 0u;
        v1.x = (4 + slot  <= mm1) ? v1.x : 0u;  v1.y = (4 + slot  <= mm1) ? v1.y : 0u;
        v2.x = (8 + slot  <= mm1) ? v2.x : 0u;  v2.y = (8 + slot  <= mm1) ? v2.y : 0u;
        v3.x = (12 + slot <= mm1) ? v3.x : 0u;  v3.y = (12 + slot <= mm1) ? v3.y : 0u;
        ACCUM8(v0);
        ACCUM8(v1);
        ACCUM8(v2);
        ACCUM8(v3);

        // deg>16 overflow (rare ~9%, uniform trip count)
        for (int i = 16; i < m; i += 16) {
            const int e0 = i + slot;
            const int e1 = i + 4 + slot;
            const int e2 = i + 8 + slot;
            const int e3 = i + 12 + slot;
            const int i0 = sidx[mst + min(e0, mm1)];
            const int i1 = sidx[mst + min(e1, mm1)];
            const int i2 = sidx[mst + min(e2, mm1)];
            const int i3 = sidx[mst + min(e3, mm1)];
            uint2 u0 = *reinterpret_cast<const uint2*>(h8p + (size_t)i0 * D);
            uint2 u1 = *reinterpret_cast<const uint2*>(h8p + (size_t)i1 * D);
            uint2 u2 = *reinterpret_cast<const uint2*>(h8p + (size_t)i2 * D);
            uint2 u3 = *reinterpret_cast<const uint2*>(h8p + (size_t)i3 * D);
            u0.x = (e0 <= mm1) ? u0.x : 0u;  u0.y = (e0 <= mm1) ? u0.y : 0u;
            u1.x = (e1 <= mm1) ? u1.x : 0u;  u1.y = (e1 <= mm1) ? u1.y : 0u;
            u2.x = (e2 <= mm1) ? u2.x : 0u;  u2.y = (e2 <= mm1) ? u2.y : 0u;
            u3.x = (e3 <= mm1) ? u3.x : 0u;  u3.y = (e3 <= mm1) ? u3.y : 0u;
            ACCUM8(u0);
            ACCUM8(u1);
            ACCUM8(u2);
            ACCUM8(u3);
        }

        int deg = m;
        if (spillN) {      // ~never taken; correctness fallback
            for (int q = 0; q < spillN; ++q) {
                int2 e = spill[q];
                if (e.x == b && ((e.y >> 17) & 63) == nl) {
                    if (slot == 0) {
                        const uint2 v = *reinterpret_cast<const uint2*>(
                            h8p + (size_t)(e.y & 0x1FFFF) * D);
                        ACCUM8(v);
                    }
                    ++deg;
                }
            }
        }

        float s[8];
#pragma unroll
        for (int j = 0; j < 4; ++j) { s[2 * j] = s01[j][0]; s[2 * j + 1] = s01[j][1]; }
#pragma unroll
        for (int j = 0; j < 8; ++j) {
            s[j] += __shfl_xor(s[j], 16);
            s[j] += __shfl_xor(s[j], 32);
        }
        if (slot == 0) {
            const float scale = 1.0f / fmaxf((float)deg, 1.0f);
            short8 o;
#pragma unroll
            for (int j = 0; j < 8; ++j) o[j] = (short)f2b(s[j] * scale);
            *reinterpret_cast<short8*>(acc + (size_t)node * D + part * 8) = o;
        }

        // rotate prefetch buffers
        pA0 = pB0; pA1 = pB1; pA2 = pB2; pA3 = pB3; mA = mB; stA = stB;
    }
#undef ISSUE
#undef ACCUM8
}

// ---------------------------------------------------------------------------
// GEMM (fused): both output types in one launch, branch on block range.
// out[N,128] = A0@W0 + A1@W1 [+ A2@W2] + bias; W* fragment-linear bf16.
// ---------------------------------------------------------------------------
__global__ __launch_bounds__(512) void gemm_all(
    const unsigned short* __restrict__ hbU,
    const unsigned short* __restrict__ accUU, const unsigned short* __restrict__ accIU,
    const short8* __restrict__ WfU0, const short8* __restrict__ WfU1,
    const short8* __restrict__ WfU2, const float* __restrict__ bsum,
    const unsigned short* __restrict__ hbI, const unsigned short* __restrict__ accUI,
    const short8* __restrict__ WfI0, const short8* __restrict__ WfI1,
    const float* __restrict__ b_ui,
    float* __restrict__ outU, float* __restrict__ outI,
    int NU, int NI, int nBlkU)
{
    __shared__ short8 lds[2048];     // 32 KB: one fragment-linear W
    const int t = threadIdx.x;
    const int w = t >> 6, l = t & 63;

    const unsigned short *A0, *A1, *A2;
    const short8 *W0, *W1, *W2;
    const float* bias; float* out; int N; int blk;
    if (blockIdx.x < nBlkU) {
        blk = blockIdx.x;
        A0 = hbU; A1 = accUU; A2 = accIU;
        W0 = WfU0; W1 = WfU1; W2 = WfU2;
        bias = bsum; out = outU; N = NU;
    } else {
        blk = blockIdx.x - nBlkU;
        A0 = hbI; A1 = accUI; A2 = nullptr;
        W0 = WfI0; W1 = WfI1; W2 = nullptr;
        bias = b_ui; out = outI; N = NI;
    }

    const int row0 = blk * 128 + w * 16;
    const int arow = row0 + (l & 15);

    f32x4 acc[8];
#pragma unroll
    for (int c = 0; c < 8; ++c) acc[c] = (f32x4){0.f, 0.f, 0.f, 0.f};

    const unsigned short* As[3] = {A0, A1, A2};
    const short8* Wfs[3] = {W0, W1, W2};
    const int nsrc = (A2 != nullptr) ? 3 : 2;

    for (int sI = 0; sI < nsrc; ++sI) {
        __syncthreads();
        const short8* Wg = Wfs[sI];
#pragma unroll
        for (int i = 0; i < 4; ++i) lds[t + i * 512] = Wg[t + i * 512];
        __syncthreads();

        const unsigned short* A = As[sI];
        short8 af[4];
        if (arow < N) {
            const unsigned short* base = A + (size_t)arow * D + ((l >> 4) << 3);
#pragma unroll
            for (int kc = 0; kc < 4; ++kc)
                af[kc] = *reinterpret_cast<const short8*>(base + kc * 32);
        } else {
            short8 z = {0, 0, 0, 0, 0, 0, 0, 0};
#pragma unroll
            for (int kc = 0; kc < 4; ++kc) af[kc] = z;
        }
#pragma unroll
        for (int kc = 0; kc < 4; ++kc)
#pragma unroll
            for (int c = 0; c < 8; ++c)
                acc[c] = __builtin_amdgcn_mfma_f32_16x16x32_bf16(
                    af[kc], lds[(c * 4 + kc) * 64 + l], acc[c], 0, 0, 0);
    }

    const int col = l & 15;
#pragma unroll
    for (int c = 0; c < 8; ++c) {
        float bv = bias[c * 16 + col];
#pragma unroll
        for (int r = 0; r < 4; ++r) {
            int row = row0 + ((l >> 4) << 2) + r;
            if (row < N)
                out[(size_t)row * D + c * 16 + col] = acc[c][r] + bv;
        }
    }
}

// ---------------------------------------------------------------------------
extern "C" void kernel_launch(void* const* d_in, const int* in_sizes, int n_in,
                              void* d_out, int out_size, void* d_ws, size_t ws_size,
                              hipStream_t stream)
{
    const float* h_user    = (const float*)d_in[0];
    const float* h_item    = (const float*)d_in[1];
    const float* Wself_uu  = (const float*)d_in[2];
    const float* Wneigh_uu = (const float*)d_in[3];
    const float* b_uu      = (const float*)d_in[4];
    const float* Wself_ui  = (const float*)d_in[5];
    const float* Wneigh_ui = (const float*)d_in[6];
    const float* b_ui      = (const float*)d_in[7];
    const float* Wself_iu  = (const float*)d_in[8];
    const float* Wneigh_iu = (const float*)d_in[9];
    const float* b_iu      = (const float*)d_in[10];
    const int* e_uu_src    = (const int*)d_in[11];
    const int* e_uu_dst    = (const int*)d_in[12];
    const int* e_ui_src    = (const int*)d_in[13];
    const int* e_ui_dst    = (const int*)d_in[14];
    const int* e_iu_src    = (const int*)d_in[15];
    const int* e_iu_dst    = (const int*)d_in[16];

    const int NU = in_sizes[0] / D;
    const int NI = in_sizes[1] / D;
    const int E_uu = in_sizes[11];
    const int E_ui = in_sizes[13];
    const int E_iu = in_sizes[15];

    const int NB0 = (NU + BSZ - 1) / BSZ;   // uu (dst=user)
    const int NB1 = (NU + BSZ - 1) / BSZ;   // iu (dst=user)
    const int NB2 = (NI + BSZ - 1) / BSZ;   // ui (dst=item)
    const int NBT = NB0 + NB1 + NB2;

    // ---- workspace carve-up (16B-aligned chunks) ----
    char* p = (char*)d_ws;
    unsigned short* hbU   = (unsigned short*)p; p += (size_t)NU * D * 2;
    unsigned short* hbI   = (unsigned short*)p; p += (size_t)NI * D * 2;
    unsigned char* h8U    = (unsigned char*)p; p += (size_t)NU * D;
    unsigned char* h8I    = (unsigned char*)p; p += (size_t)NI * D;
    unsigned short* accUU = (unsigned short*)p; p += (size_t)NU * D * 2;
    unsigned short* accIU = (unsigned short*)p; p += (size_t)NU * D * 2;
    unsigned short* accUI = (unsigned short*)p; p += (size_t)NI * D * 2;
    short8* WfU0 = (short8*)p; p += 32768;
    short8* WfU1 = (short8*)p; p += 32768;
    short8* WfU2 = (short8*)p; p += 32768;
    short8* WfI0 = (short8*)p; p += 32768;
    short8* WfI1 = (short8*)p; p += 32768;
    float* bsum  = (float*)p;  p += 512;
    int* cursors = (int*)p; p += (size_t)((NBT + 3) & ~3) * 4;
    int* spillCnt = (int*)p; p += 16;
    int2* spill  = (int2*)p; p += (size_t)SPILL_MAX * 8;
    int* stg     = (int*)p; p += (size_t)NBT * CAPG * 4;

    // zero cursors + spill counter (contiguous, ~9.5 KB)
    hipMemsetAsync(cursors, 0, ((size_t)((NBT + 3) & ~3) + 16) * sizeof(int), stream);

    const int nU8 = NU * D / 8, nI8 = NI * D / 8;
    const int nConvH = (nU8 + nI8 + 1023) / 1024;
    const int nblk0 = (E_uu + CHUNK - 1) / CHUNK;
    const int nblk1 = (E_iu + CHUNK - 1) / CHUNK;
    const int nblk2 = (E_ui + CHUNK - 1) / CHUNK;
    const int nblkS = nblk0 + nblk1 + nblk2;

    prep_scatter<<<nblkS + nConvH + 11, 1024, 0, stream>>>(
        e_uu_src, e_uu_dst, E_uu,
        e_iu_src, e_iu_dst, E_iu,
        e_ui_src, e_ui_dst, E_ui,
        NB0, NB1, cursors, stg, spill, spillCnt, nblk0, nblk1, nblkS,
        h_user, h_item, nU8, nI8, hbU, hbI, h8U, h8I,
        Wself_uu, Wself_iu, Wneigh_uu, Wneigh_iu, Wself_ui, Wneigh_ui,
        WfU0, WfU1, WfU2, WfI0, WfI1,
        b_uu, b_iu, bsum, nConvH);

    gather_bucket<<<NBT, 256, 0, stream>>>(
        h8U, h8I, stg, cursors, spill, spillCnt,
        accUU, accIU, accUI, NB0, NB1, NU, NI);

    float* out_user = (float*)d_out;
    float* out_item = out_user + (size_t)NU * D;
    const int nBlkU = (NU + 127) / 128, nBlkI = (NI + 127) / 128;

    gemm_all<<<nBlkU + nBlkI, 512, 0, stream>>>(
        hbU, accUU, accIU, WfU0, WfU1, WfU2, bsum,
        hbI, accUI, WfI0, WfI1, b_ui,
        out_user, out_item, NU, NI, nBlkU);
}